// Round 1
// baseline (26347.763 us; speedup 1.0000x reference)
//
#include <hip/hip_runtime.h>

#define H6   3072
#define TT   1000
#define NWG  192
#define NTHR 256

typedef short bf16x8 __attribute__((ext_vector_type(8)));
typedef float f32x4  __attribute__((ext_vector_type(4)));

// ---- bf16 helpers (manual bits; RNE) ----
__device__ __forceinline__ unsigned short f2bf(float f) {
  unsigned u = __float_as_uint(f);
  return (unsigned short)((u + 0x7fffu + ((u >> 16) & 1u)) >> 16);
}
__device__ __forceinline__ float bf2f(unsigned short s) {
  return __uint_as_float(((unsigned)s) << 16);
}

// ---- workspace layout (bytes) ----
// Whi  : 2621440 bf16 = 5242880        @ 0
// Wlo  : 5242880                        @ 5242880
// hhi  : 2*49152 bf16 = 196608          @ 10485760
// hlo  : 196608                         @ 10682368
// fc_v : 512 f32 = 2048                 @ 10878976
// bar  : 2 u32                          @ 10881024
#define WS_WLO 5242880
#define WS_HHI 10485760
#define WS_HLO 10682368
#define WS_FCV 10878976
#define WS_BAR 10881024

// ============================ prep kernel ============================
// Builds effective block weights (masks/signs/relu baked in) split into
// bf16 hi+lo, converts h0=hn into split form, computes v = relu(fc1)@relu(fc2)
// for the alm rows, and resets the barrier.
__global__ void prep_kernel(
    const float* __restrict__ hn, const float* __restrict__ fixed_,
    const float* __restrict__ thal2alm_w, const float* __restrict__ thal2str_w,
    const float* __restrict__ alm2alm_w, const float* __restrict__ alm2str_w,
    const float* __restrict__ str2snr_w, const float* __restrict__ str2gpe_w,
    const float* __restrict__ gpe2stn_w, const float* __restrict__ stn2snr_w,
    const float* __restrict__ snr2thal_w,
    const float* __restrict__ fc1, const float* __restrict__ fc2,
    unsigned short* __restrict__ Whi, unsigned short* __restrict__ Wlo,
    unsigned short* __restrict__ hhi, unsigned short* __restrict__ hlo,
    float* __restrict__ fc_vec, unsigned* __restrict__ bar)
{
  int gid = blockIdx.x * blockDim.x + threadIdx.x;
  int stride = gridDim.x * blockDim.x;
  const int nbt[6]  = {3,1,1,2,1,2};
  const int woff[6] = {0,786432,1048576,1310720,1835008,2097152};
  for (int idx = gid; idx < 2621440; idx += stride) {
    int u = idx >> 18;   // /262144
    int t = (u<3)?0:((u<4)?1:((u<5)?2:((u<7)?3:((u<8)?4:5))));
    int local = idx - woff[t];
    int ktot = nbt[t] << 9;
    int j  = local / ktot;
    int kx = local - j*ktot;
    int bi = kx >> 9, kk = kx & 511;
    int src = j*512 + kk;
    float w;
    if (t == 0) {       // str rows: [str | thal | alm]
      if (bi == 0)      w = -fixed_[src];                                      // -str2str_fixed
      else if (bi == 1) w = (j >= 128 && j < 384) ? fmaxf(thal2str_w[src],0.f) : 0.f;
      else              w = (kk < 359) ? fmaxf(alm2str_w[src],0.f) : 0.f;
    } else if (t == 1)  w = (kk >= 256) ? -fmaxf(str2gpe_w[src],0.f) : 0.f;    // gpe <- str
    else if (t == 2)    w = -fmaxf(gpe2stn_w[src],0.f);                        // stn <- gpe
    else if (t == 3)    w = (bi == 0) ? ((kk < 256) ? -fmaxf(str2snr_w[src],0.f) : 0.f)
                                      : fmaxf(stn2snr_w[src],0.f);             // snr <- str,stn
    else if (t == 4)    w = -fmaxf(snr2thal_w[src],0.f);                       // thal <- snr
    else                w = (bi == 0) ? fmaxf(thal2alm_w[src],0.f)
                                      : fmaxf(alm2alm_w[src],0.f) * ((kk < 359) ? 1.f : -1.f);
    unsigned short hi = f2bf(w);
    Whi[idx] = hi;
    Wlo[idx] = f2bf(w - bf2f(hi));
  }
  for (int idx = gid; idx < 49152; idx += stride) {
    float v = hn[idx];
    unsigned short hi = f2bf(v);
    hhi[idx] = hi;
    hlo[idx] = f2bf(v - bf2f(hi));
  }
  int wid = gid >> 6, lane = gid & 63;
  if (wid < 512) {
    float s = 0.f;
    for (int m = lane; m < 512; m += 64)
      s += fmaxf(fc1[(2560 + wid)*512 + m], 0.f) * fmaxf(fc2[m], 0.f);
    for (int off = 32; off; off >>= 1) s += __shfl_down(s, off);
    if (lane == 0) fc_vec[wid] = s;
  }
  if (gid == 0) { bar[0] = 0u; bar[1] = 0u; }
}

// ============================ scan kernel ============================
__device__ __forceinline__ void grid_barrier(unsigned* bar) {
  __syncthreads();
  if (threadIdx.x == 0) {
    unsigned g = __hip_atomic_load(&bar[1], __ATOMIC_RELAXED, __HIP_MEMORY_SCOPE_AGENT);
    unsigned prev = __hip_atomic_fetch_add(&bar[0], 1u, __ATOMIC_ACQ_REL, __HIP_MEMORY_SCOPE_AGENT);
    if (prev == NWG - 1) {
      __hip_atomic_store(&bar[0], 0u, __ATOMIC_RELAXED, __HIP_MEMORY_SCOPE_AGENT);
      __hip_atomic_fetch_add(&bar[1], 1u, __ATOMIC_RELEASE, __HIP_MEMORY_SCOPE_AGENT);
    } else {
      while (__hip_atomic_load(&bar[1], __ATOMIC_RELAXED, __HIP_MEMORY_SCOPE_AGENT) == g)
        __builtin_amdgcn_s_sleep(1);
      (void)__hip_atomic_load(&bar[1], __ATOMIC_ACQUIRE, __HIP_MEMORY_SCOPE_AGENT);
    }
  }
  __syncthreads();
}

template<int NB>
__device__ __forceinline__ void scan_body(
    const float* __restrict__ inp, const float* __restrict__ hn,
    const float* __restrict__ inhib, const float* __restrict__ inp_weight,
    const unsigned short* __restrict__ Whi_g, const unsigned short* __restrict__ Wlo_g,
    unsigned short* __restrict__ hhi_g, unsigned short* __restrict__ hlo_g,
    float* __restrict__ rnn_out, unsigned* __restrict__ bar,
    char* smem, int type, int tile, int kb0, int kb1, int kb2, int woff)
{
  const int tid = threadIdx.x, lane = tid & 63, wave = tid >> 6;
  const int ktot = NB << 9;
  const int jb_local = tile << 4;
  const int jb_glob  = (type << 9) + jb_local;
  const int kb[3] = {kb0, kb1, kb2};

  unsigned short* Wsh_hi = (unsigned short*)(smem);
  unsigned short* Wsh_lo = (unsigned short*)(smem + 49152);
  unsigned short* hsh_hi = (unsigned short*)(smem + 98304);
  unsigned short* hsh_lo = (unsigned short*)(smem + 114688);
  float*          red    = (float*)(smem + 131072);

  // ---- load W tile into LDS once (16B-chunk xor swizzle to kill conflicts) ----
  {
    const int cpr = ktot >> 3;                 // 16B chunks per row
    const unsigned short* srch = Whi_g + woff + jb_local * ktot;
    const unsigned short* srcl = Wlo_g + woff + jb_local * ktot;
    for (int c = tid; c < 16 * cpr; c += NTHR) {
      int j = c / cpr, kc = c - j * cpr;
      uint4 vh = *(const uint4*)(srch + j * ktot + (kc << 3));
      uint4 vl = *(const uint4*)(srcl + j * ktot + (kc << 3));
      int kcs = kc ^ (j & 7);
      *(uint4*)((char*)Wsh_hi + j * (ktot << 1) + (kcs << 4)) = vh;
      *(uint4*)((char*)Wsh_lo + j * (ktot << 1) + (kcs << 4)) = vl;
    }
  }

  // ---- per-lane epilogue constants (wave0 uses; C/D layout: col=b=lane&15, row=quad*4+r) ----
  const int b_ep = lane & 15, quad = lane >> 4;
  const bool has_inp = (type == 0) && (jb_local >= 128) && (jb_local < 384);
  int jg[4]; float hprev[4], dbase[4], iw[4][4];
  #pragma unroll
  for (int r = 0; r < 4; ++r) {
    jg[r] = jb_glob + (quad << 2) + r;
    hprev[r] = hn[b_ep * H6 + jg[r]];
    float tn = ((jg[r] >= 512 && jg[r] < 1536) || (jg[r] >= 2048 && jg[r] < 2560)) ? 1.f : 0.f;
    dbase[r] = inhib[b_ep * H6 + jg[r]] + tn;
    #pragma unroll
    for (int i = 0; i < 4; ++i)
      iw[r][i] = has_inp ? fmaxf(inp_weight[i * H6 + jg[r]], 0.f) : 0.f;
  }
  __syncthreads();

  int p = 0;
  for (int t = 0; t < TT; ++t) {
    f32x4 acc0 = {0,0,0,0}, acc1 = {0,0,0,0}, acc2 = {0,0,0,0};

    // issue ALL h-block global loads up front (one LLC latency, not NB)
    uint4 vh[NB][4], vl[NB][4];
    #pragma unroll
    for (int bi = 0; bi < NB; ++bi) {
      const unsigned short* gh = hhi_g + p * 49152 + (kb[bi] << 9);
      const unsigned short* gl = hlo_g + p * 49152 + (kb[bi] << 9);
      #pragma unroll
      for (int i = 0; i < 4; ++i) {
        int b = wave + (i << 2);
        vh[bi][i] = *(const uint4*)(gh + b * H6 + (lane << 3));
        vl[bi][i] = *(const uint4*)(gl + b * H6 + (lane << 3));
      }
    }

    #pragma unroll
    for (int bi = 0; bi < NB; ++bi) {
      if (bi) __syncthreads();                    // prev block's mfma done before overwrite
      #pragma unroll
      for (int i = 0; i < 4; ++i) {
        int b = wave + (i << 2);
        int kcs = lane ^ (b & 7);
        *(uint4*)((char*)hsh_hi + (b << 10) + (kcs << 4)) = vh[bi][i];
        *(uint4*)((char*)hsh_lo + (b << 10) + (kcs << 4)) = vl[bi][i];
      }
      __syncthreads();
      // wave handles k in [wave*128, wave*128+128) of this block, chunks of 32
      const int row = lane & 15;                  // A row = j ; B row = b (same lane id)
      const int wpitch = ktot << 1;
      #pragma unroll
      for (int c = 0; c < 4; ++c) {
        int kca = (bi << 6) + (wave << 4) + (c << 2) + quad;   // W chunk idx on concat axis
        int hca = (wave << 4) + (c << 2) + quad;               // h chunk idx within block
        bf16x8 ahi = *(const bf16x8*)((char*)Wsh_hi + row * wpitch + ((kca ^ (row & 7)) << 4));
        bf16x8 alo = *(const bf16x8*)((char*)Wsh_lo + row * wpitch + ((kca ^ (row & 7)) << 4));
        bf16x8 bhi = *(const bf16x8*)((char*)hsh_hi + (row << 10) + ((hca ^ (row & 7)) << 4));
        bf16x8 blo = *(const bf16x8*)((char*)hsh_lo + (row << 10) + ((hca ^ (row & 7)) << 4));
        acc0 = __builtin_amdgcn_mfma_f32_16x16x32_bf16(ahi, bhi, acc0, 0, 0, 0);
        acc1 = __builtin_amdgcn_mfma_f32_16x16x32_bf16(ahi, blo, acc1, 0, 0, 0);
        acc2 = __builtin_amdgcn_mfma_f32_16x16x32_bf16(alo, bhi, acc2, 0, 0, 0);
      }
    }
    f32x4 acc = acc0 + acc1 + acc2;

    // ---- cross-wave reduce (4 partials per output) ----
    if (wave) *(f32x4*)(red + ((wave - 1) * 64 + lane) * 4) = acc;
    __syncthreads();
    if (wave == 0) {
      f32x4 r0 = *(const f32x4*)(red + lane * 4);
      f32x4 r1 = *(const f32x4*)(red + (64 + lane) * 4);
      f32x4 r2 = *(const f32x4*)(red + (128 + lane) * 4);
      acc = acc + r0 + r1 + r2;
      float proj[4] = {0.f, 0.f, 0.f, 0.f};
      if (has_inp) {
        const float4 xi = *(const float4*)(inp + (b_ep * TT + t) * 4);
        #pragma unroll
        for (int r = 0; r < 4; ++r)
          proj[r] = xi.x*iw[r][0] + xi.y*iw[r][1] + xi.z*iw[r][2] + xi.w*iw[r][3];
      }
      unsigned short* oh = hhi_g + (p ^ 1) * 49152;
      unsigned short* ol = hlo_g + (p ^ 1) * 49152;
      #pragma unroll
      for (int r = 0; r < 4; ++r) {
        float pre = hprev[r] + 0.01f * (acc[r] + dbase[r] + proj[r] - hprev[r]);
        float hv = fmaxf(pre, 0.f);
        hprev[r] = hv;
        rnn_out[(size_t)(b_ep * TT + t) * H6 + jg[r]] = hv;
        unsigned short hi = f2bf(hv);
        oh[b_ep * H6 + jg[r]] = hi;
        ol[b_ep * H6 + jg[r]] = f2bf(hv - bf2f(hi));
      }
    }
    grid_barrier(bar);
    p ^= 1;
  }
}

__global__ void __launch_bounds__(NTHR, 1) scan_kernel(
    const float* __restrict__ inp, const float* __restrict__ hn,
    const float* __restrict__ inhib, const float* __restrict__ inp_weight,
    const unsigned short* __restrict__ Whi_g, const unsigned short* __restrict__ Wlo_g,
    unsigned short* __restrict__ hhi_g, unsigned short* __restrict__ hlo_g,
    float* __restrict__ rnn_out, unsigned* __restrict__ bar)
{
  extern __shared__ char smem[];
  int wg = blockIdx.x;
  int type = wg >> 5, tile = wg & 31;
  switch (type) {
    case 0: scan_body<3>(inp,hn,inhib,inp_weight,Whi_g,Wlo_g,hhi_g,hlo_g,rnn_out,bar,smem,0,tile,0,4,5,0);       break;
    case 1: scan_body<1>(inp,hn,inhib,inp_weight,Whi_g,Wlo_g,hhi_g,hlo_g,rnn_out,bar,smem,1,tile,0,0,0,786432);  break;
    case 2: scan_body<1>(inp,hn,inhib,inp_weight,Whi_g,Wlo_g,hhi_g,hlo_g,rnn_out,bar,smem,2,tile,1,0,0,1048576); break;
    case 3: scan_body<2>(inp,hn,inhib,inp_weight,Whi_g,Wlo_g,hhi_g,hlo_g,rnn_out,bar,smem,3,tile,0,2,0,1310720); break;
    case 4: scan_body<1>(inp,hn,inhib,inp_weight,Whi_g,Wlo_g,hhi_g,hlo_g,rnn_out,bar,smem,4,tile,3,0,0,1835008); break;
    default:scan_body<2>(inp,hn,inhib,inp_weight,Whi_g,Wlo_g,hhi_g,hlo_g,rnn_out,bar,smem,5,tile,4,5,0,2097152); break;
  }
}

// ============================ head kernel ============================
// out[b,t] = sigmoid( dot(rnn_out[b,t,2560:3072], v) ) ; also hn_last copy.
__global__ void head_kernel(const float* __restrict__ rnn, const float* __restrict__ fc_vec,
                            float* __restrict__ out, float* __restrict__ hn_last)
{
  int lane = threadIdx.x & 63;
  if (blockIdx.x < 4000) {
    int wid = blockIdx.x * 4 + (threadIdx.x >> 6);   // < 16000
    int b = wid / 1000, t = wid - b * 1000;
    const float* rp = rnn + (size_t)(b * 1000 + t) * H6 + 2560 + lane * 8;
    float4 a0 = *(const float4*)rp, a1 = *(const float4*)(rp + 4);
    const float* vp = fc_vec + lane * 8;
    float4 v0 = *(const float4*)vp, v1 = *(const float4*)(vp + 4);
    float s = a0.x*v0.x + a0.y*v0.y + a0.z*v0.z + a0.w*v0.w
            + a1.x*v1.x + a1.y*v1.y + a1.z*v1.z + a1.w*v1.w;
    for (int off = 32; off; off >>= 1) s += __shfl_down(s, off);
    if (lane == 0) out[b * 1000 + t] = 1.f / (1.f + expf(-s));
  } else {
    int idx = (blockIdx.x - 4000) * NTHR + threadIdx.x;   // < 49152
    int b = idx / H6, j = idx - b * H6;
    hn_last[idx] = rnn[(size_t)(b * 1000 + 999) * H6 + j];
  }
}

// ============================ x broadcast ============================
__global__ void bcast_kernel(const float* __restrict__ x,
                             float* __restrict__ x_last, float* __restrict__ x_out)
{
  int gid = blockIdx.x * blockDim.x + threadIdx.x;
  int stride = gridDim.x * blockDim.x;
  for (int i = gid; i < 12288; i += stride)
    ((float4*)x_last)[i] = ((const float4*)x)[i];
  for (int i = gid; i < 12288000; i += stride) {
    int b = i / 768000;
    int r = i - b * 768000;
    int j4 = r % 768;
    ((float4*)x_out)[i] = ((const float4*)x)[b * 768 + j4];
  }
}

// ============================ launcher ============================
extern "C" void kernel_launch(void* const* d_in, const int* in_sizes, int n_in,
                              void* d_out, int out_size, void* d_ws, size_t ws_size,
                              hipStream_t stream) {
  (void)in_sizes; (void)n_in; (void)out_size; (void)ws_size;
  const float* inp        = (const float*)d_in[0];
  const float* hn         = (const float*)d_in[1];
  const float* x          = (const float*)d_in[2];
  const float* inhib      = (const float*)d_in[3];
  /* d_in[4] = str2str_w — unused by the reference (D = -I uses str2str_fixed) */
  const float* thal2alm_w = (const float*)d_in[5];
  const float* thal2str_w = (const float*)d_in[6];
  const float* alm2alm_w  = (const float*)d_in[7];
  const float* alm2str_w  = (const float*)d_in[8];
  const float* str2snr_w  = (const float*)d_in[9];
  const float* str2gpe_w  = (const float*)d_in[10];
  const float* gpe2stn_w  = (const float*)d_in[11];
  const float* stn2snr_w  = (const float*)d_in[12];
  const float* snr2thal_w = (const float*)d_in[13];
  const float* inp_weight = (const float*)d_in[14];
  const float* fc1        = (const float*)d_in[15];
  const float* fc2        = (const float*)d_in[16];
  const float* fixed_     = (const float*)d_in[17];

  float* out_p   = (float*)d_out;
  float* hn_last = out_p + 16000;
  float* rnn     = hn_last + 49152;
  float* x_last  = rnn + 49152000;
  float* x_out   = x_last + 49152;

  char* ws = (char*)d_ws;
  unsigned short* Whi = (unsigned short*)(ws);
  unsigned short* Wlo = (unsigned short*)(ws + WS_WLO);
  unsigned short* hhi = (unsigned short*)(ws + WS_HHI);
  unsigned short* hlo = (unsigned short*)(ws + WS_HLO);
  float* fc_vec = (float*)(ws + WS_FCV);
  unsigned* bar = (unsigned*)(ws + WS_BAR);

  hipFuncSetAttribute((const void*)scan_kernel,
                      hipFuncAttributeMaxDynamicSharedMemorySize, 135168);

  prep_kernel<<<2048, NTHR, 0, stream>>>(hn, fixed_, thal2alm_w, thal2str_w, alm2alm_w,
      alm2str_w, str2snr_w, str2gpe_w, gpe2stn_w, stn2snr_w, snr2thal_w, fc1, fc2,
      Whi, Wlo, hhi, hlo, fc_vec, bar);
  scan_kernel<<<NWG, NTHR, 134144, stream>>>(inp, hn, inhib, inp_weight,
      Whi, Wlo, hhi, hlo, rnn, bar);
  head_kernel<<<4192, NTHR, 0, stream>>>(rnn, fc_vec, out_p, hn_last);
  bcast_kernel<<<4096, NTHR, 0, stream>>>(x, x_last, x_out);
}

// Round 2
// 8985.844 us; speedup vs baseline: 2.9321x; 2.9321x over previous
//
#include <hip/hip_runtime.h>

#define H6   3072
#define TT   1000
#define NWG  192
#define NTHR 256

typedef short bf16x8 __attribute__((ext_vector_type(8)));
typedef float f32x4  __attribute__((ext_vector_type(4)));

// ---- bf16 helpers (manual bits; RNE) ----
__device__ __forceinline__ unsigned short f2bf(float f) {
  unsigned u = __float_as_uint(f);
  return (unsigned short)((u + 0x7fffu + ((u >> 16) & 1u)) >> 16);
}
__device__ __forceinline__ float bf2f(unsigned short s) {
  return __uint_as_float(((unsigned)s) << 16);
}

// ---- workspace layout (bytes) ----
// Whi   : 2621440 bf16 = 5242880       @ 0
// Wlo   : 5242880                       @ 5242880
// ringH : 8 slots * 49152 bf16 = 786432 @ 10485760
// ringL : 786432                        @ 11272192
// fc_v  : 512 f32 = 2048                @ 12058624
// cnt   : 48 u32 = 192                  @ 12060672
#define WS_WLO 5242880
#define WS_RHI 10485760
#define WS_RLO 11272192
#define WS_FCV 12058624
#define WS_CNT 12060672

// ============================ prep kernel ============================
__global__ void prep_kernel(
    const float* __restrict__ hn, const float* __restrict__ fixed_,
    const float* __restrict__ thal2alm_w, const float* __restrict__ thal2str_w,
    const float* __restrict__ alm2alm_w, const float* __restrict__ alm2str_w,
    const float* __restrict__ str2snr_w, const float* __restrict__ str2gpe_w,
    const float* __restrict__ gpe2stn_w, const float* __restrict__ stn2snr_w,
    const float* __restrict__ snr2thal_w,
    const float* __restrict__ fc1, const float* __restrict__ fc2,
    unsigned short* __restrict__ Whi, unsigned short* __restrict__ Wlo,
    unsigned short* __restrict__ ringH, unsigned short* __restrict__ ringL,
    float* __restrict__ fc_vec, unsigned* __restrict__ cnt)
{
  int gid = blockIdx.x * blockDim.x + threadIdx.x;
  int stride = gridDim.x * blockDim.x;
  const int nbt[6]  = {3,1,1,2,1,2};
  const int woff[6] = {0,786432,1048576,1310720,1835008,2097152};
  for (int idx = gid; idx < 2621440; idx += stride) {
    int u = idx >> 18;
    int t = (u<3)?0:((u<4)?1:((u<5)?2:((u<7)?3:((u<8)?4:5))));
    int local = idx - woff[t];
    int ktot = nbt[t] << 9;
    int j  = local / ktot;
    int kx = local - j*ktot;
    int bi = kx >> 9, kk = kx & 511;
    int src = j*512 + kk;
    float w;
    if (t == 0) {       // str rows: [str | thal | alm]
      if (bi == 0)      w = -fixed_[src];
      else if (bi == 1) w = (j >= 128 && j < 384) ? fmaxf(thal2str_w[src],0.f) : 0.f;
      else              w = (kk < 359) ? fmaxf(alm2str_w[src],0.f) : 0.f;
    } else if (t == 1)  w = (kk >= 256) ? -fmaxf(str2gpe_w[src],0.f) : 0.f;
    else if (t == 2)    w = -fmaxf(gpe2stn_w[src],0.f);
    else if (t == 3)    w = (bi == 0) ? ((kk < 256) ? -fmaxf(str2snr_w[src],0.f) : 0.f)
                                      : fmaxf(stn2snr_w[src],0.f);
    else if (t == 4)    w = -fmaxf(snr2thal_w[src],0.f);
    else                w = (bi == 0) ? fmaxf(thal2alm_w[src],0.f)
                                      : fmaxf(alm2alm_w[src],0.f) * ((kk < 359) ? 1.f : -1.f);
    unsigned short hi = f2bf(w);
    Whi[idx] = hi;
    Wlo[idx] = f2bf(w - bf2f(hi));
  }
  // h0 = hn goes into ring slot 7 (== step -1 mod 8)
  for (int idx = gid; idx < 49152; idx += stride) {
    float v = hn[idx];
    unsigned short hi = f2bf(v);
    ringH[7*49152 + idx] = hi;
    ringL[7*49152 + idx] = f2bf(v - bf2f(hi));
  }
  int wid = gid >> 6, lane = gid & 63;
  if (wid < 512) {
    float s = 0.f;
    for (int m = lane; m < 512; m += 64)
      s += fmaxf(fc1[(2560 + wid)*512 + m], 0.f) * fmaxf(fc2[m], 0.f);
    for (int off = 32; off; off >>= 1) s += __shfl_down(s, off);
    if (lane == 0) fc_vec[wid] = s;
  }
  if (gid < 48) cnt[gid] = 0u;
}

// ============================ scan kernel ============================
// Barrier-free dataflow: region r publishes arrival count cnt[r*8 + t&7]
// (monotone; slot reuse every 8 steps). Consumers spin on their source
// regions only. Drift bound: every producer->consumer edge has a return
// path of length <= 4  =>  max inter-WG step drift 4 < 8 slots. All h
// exchange uses relaxed AGENT-scope atomics (per-access sc1 coherence,
// NO bulk L2 writeback/invalidate -- that flush was 26us/step in R0).
template<int NB>
__device__ __forceinline__ void scan_body(
    const float* __restrict__ inp, const float* __restrict__ hn,
    const float* __restrict__ inhib, const float* __restrict__ inp_weight,
    const unsigned short* __restrict__ Whi_g, const unsigned short* __restrict__ Wlo_g,
    unsigned short* __restrict__ ringH, unsigned short* __restrict__ ringL,
    float* __restrict__ rnn_out, unsigned* __restrict__ cnt,
    char* smem, int type, int tile, int kb0, int kb1, int kb2, int woff)
{
  const int tid = threadIdx.x, lane = tid & 63, wave = tid >> 6;
  const int ktot = NB << 9;
  const int jb_local = tile << 4;
  const int jb_glob  = (type << 9) + jb_local;
  const int kb[3] = {kb0, kb1, kb2};

  unsigned short* Wsh_hi = (unsigned short*)(smem);
  unsigned short* Wsh_lo = (unsigned short*)(smem + 49152);
  unsigned short* hsh_hi = (unsigned short*)(smem + 98304);
  unsigned short* hsh_lo = (unsigned short*)(smem + 114688);
  float*          red    = (float*)(smem + 131072);

  // ---- load W tile into LDS once (16B-chunk xor swizzle) ----
  {
    const int cpr = ktot >> 3;
    const unsigned short* srch = Whi_g + woff + jb_local * ktot;
    const unsigned short* srcl = Wlo_g + woff + jb_local * ktot;
    for (int c = tid; c < 16 * cpr; c += NTHR) {
      int j = c / cpr, kc = c - j * cpr;
      uint4 vh = *(const uint4*)(srch + j * ktot + (kc << 3));
      uint4 vl = *(const uint4*)(srcl + j * ktot + (kc << 3));
      int kcs = kc ^ (j & 7);
      *(uint4*)((char*)Wsh_hi + j * (ktot << 1) + (kcs << 4)) = vh;
      *(uint4*)((char*)Wsh_lo + j * (ktot << 1) + (kcs << 4)) = vl;
    }
  }

  // ---- per-lane epilogue constants (wave0; C/D: col=b=lane&15, row=quad*4+r) ----
  const int b_ep = lane & 15, quad = lane >> 4;
  const bool has_inp = (type == 0) && (jb_local >= 128) && (jb_local < 384);
  int jg[4]; float hprev[4], dbase[4], iw[4][4];
  #pragma unroll
  for (int r = 0; r < 4; ++r) {
    jg[r] = jb_glob + (quad << 2) + r;
    hprev[r] = hn[b_ep * H6 + jg[r]];
    float tn = ((jg[r] >= 512 && jg[r] < 1536) || (jg[r] >= 2048 && jg[r] < 2560)) ? 1.f : 0.f;
    dbase[r] = inhib[b_ep * H6 + jg[r]] + tn;
    #pragma unroll
    for (int i = 0; i < 4; ++i)
      iw[r][i] = has_inp ? fmaxf(inp_weight[i * H6 + jg[r]], 0.f) : 0.f;
  }
  __syncthreads();

  for (int t = 0; t < TT; ++t) {
    // ---- wait for source regions to publish step t-1 ----
    if (t > 0 && tid < NB) {
      unsigned expected = 32u * ((((unsigned)(t - 1)) >> 3) + 1u);
      const unsigned* f = &cnt[(kb[tid] << 3) + ((t - 1) & 7)];
      while (__hip_atomic_load(f, __ATOMIC_RELAXED, __HIP_MEMORY_SCOPE_AGENT) < expected)
        __builtin_amdgcn_s_sleep(2);
    }
    __syncthreads();   // sync A: gates h loads; also orders red reuse

    const int s_rd = (t + 7) & 7;  // (t-1) mod 8 ; t=0 -> slot 7 (hn from prep)
    // ---- load h for all source blocks (cache-bypassing, pipelined) ----
    unsigned long long vh[NB][4][2], vl[NB][4][2];
    #pragma unroll
    for (int bi = 0; bi < NB; ++bi) {
      const unsigned short* gh = ringH + s_rd * 49152 + (kb[bi] << 9);
      const unsigned short* gl = ringL + s_rd * 49152 + (kb[bi] << 9);
      #pragma unroll
      for (int i = 0; i < 4; ++i) {
        int b = wave + (i << 2);
        const unsigned long long* ph = (const unsigned long long*)(gh + b * H6 + (lane << 3));
        const unsigned long long* pl = (const unsigned long long*)(gl + b * H6 + (lane << 3));
        vh[bi][i][0] = __hip_atomic_load(ph,     __ATOMIC_RELAXED, __HIP_MEMORY_SCOPE_AGENT);
        vh[bi][i][1] = __hip_atomic_load(ph + 1, __ATOMIC_RELAXED, __HIP_MEMORY_SCOPE_AGENT);
        vl[bi][i][0] = __hip_atomic_load(pl,     __ATOMIC_RELAXED, __HIP_MEMORY_SCOPE_AGENT);
        vl[bi][i][1] = __hip_atomic_load(pl + 1, __ATOMIC_RELAXED, __HIP_MEMORY_SCOPE_AGENT);
      }
    }

    f32x4 acc0 = {0,0,0,0}, acc1 = {0,0,0,0}, acc2 = {0,0,0,0};
    #pragma unroll
    for (int bi = 0; bi < NB; ++bi) {
      if (bi) __syncthreads();
      #pragma unroll
      for (int i = 0; i < 4; ++i) {
        int b = wave + (i << 2);
        int kcs = lane ^ (b & 7);
        *(unsigned long long*)((char*)hsh_hi + (b << 10) + (kcs << 4))     = vh[bi][i][0];
        *(unsigned long long*)((char*)hsh_hi + (b << 10) + (kcs << 4) + 8) = vh[bi][i][1];
        *(unsigned long long*)((char*)hsh_lo + (b << 10) + (kcs << 4))     = vl[bi][i][0];
        *(unsigned long long*)((char*)hsh_lo + (b << 10) + (kcs << 4) + 8) = vl[bi][i][1];
      }
      __syncthreads();
      const int row = lane & 15;
      const int wpitch = ktot << 1;
      #pragma unroll
      for (int c = 0; c < 4; ++c) {
        int kca = (bi << 6) + (wave << 4) + (c << 2) + quad;
        int hca = (wave << 4) + (c << 2) + quad;
        bf16x8 ahi = *(const bf16x8*)((char*)Wsh_hi + row * wpitch + ((kca ^ (row & 7)) << 4));
        bf16x8 alo = *(const bf16x8*)((char*)Wsh_lo + row * wpitch + ((kca ^ (row & 7)) << 4));
        bf16x8 bhi = *(const bf16x8*)((char*)hsh_hi + (row << 10) + ((hca ^ (row & 7)) << 4));
        bf16x8 blo = *(const bf16x8*)((char*)hsh_lo + (row << 10) + ((hca ^ (row & 7)) << 4));
        acc0 = __builtin_amdgcn_mfma_f32_16x16x32_bf16(ahi, bhi, acc0, 0, 0, 0);
        acc1 = __builtin_amdgcn_mfma_f32_16x16x32_bf16(ahi, blo, acc1, 0, 0, 0);
        acc2 = __builtin_amdgcn_mfma_f32_16x16x32_bf16(alo, bhi, acc2, 0, 0, 0);
      }
    }
    f32x4 acc = acc0 + acc1 + acc2;

    // ---- cross-wave reduce ----
    if (wave) *(f32x4*)(red + ((wave - 1) * 64 + lane) * 4) = acc;
    __syncthreads();   // sync R
    if (wave == 0) {
      f32x4 r0 = *(const f32x4*)(red + lane * 4);
      f32x4 r1 = *(const f32x4*)(red + (64 + lane) * 4);
      f32x4 r2 = *(const f32x4*)(red + (128 + lane) * 4);
      acc = acc + r0 + r1 + r2;
      float proj[4] = {0.f, 0.f, 0.f, 0.f};
      if (has_inp) {
        const float4 xi = *(const float4*)(inp + (b_ep * TT + t) * 4);
        #pragma unroll
        for (int r = 0; r < 4; ++r)
          proj[r] = xi.x*iw[r][0] + xi.y*iw[r][1] + xi.z*iw[r][2] + xi.w*iw[r][3];
      }
      float4 hv4;
      unsigned long long ph = 0ull, pl = 0ull;
      #pragma unroll
      for (int r = 0; r < 4; ++r) {
        float pre = hprev[r] + 0.01f * (acc[r] + dbase[r] + proj[r] - hprev[r]);
        float hv = fmaxf(pre, 0.f);
        hprev[r] = hv;
        ((float*)&hv4)[r] = hv;
        unsigned short hi = f2bf(hv);
        ph |= ((unsigned long long)hi) << (16 * r);
        pl |= ((unsigned long long)f2bf(hv - bf2f(hi))) << (16 * r);
      }
      *(float4*)(rnn_out + (size_t)(b_ep * TT + t) * H6 + jg[0]) = hv4;  // plain, stays in L2
      unsigned long long* oh = (unsigned long long*)(ringH + (t & 7) * 49152 + b_ep * H6 + jg[0]);
      unsigned long long* ol = (unsigned long long*)(ringL + (t & 7) * 49152 + b_ep * H6 + jg[0]);
      __hip_atomic_store(oh, ph, __ATOMIC_RELAXED, __HIP_MEMORY_SCOPE_AGENT);
      __hip_atomic_store(ol, pl, __ATOMIC_RELAXED, __HIP_MEMORY_SCOPE_AGENT);
      asm volatile("s_waitcnt vmcnt(0)" ::: "memory");  // drain h stores before publish
      if (lane == 0)
        __hip_atomic_fetch_add(&cnt[(type << 3) + (t & 7)], 1u,
                               __ATOMIC_RELAXED, __HIP_MEMORY_SCOPE_AGENT);
    }
  }
}

__global__ void __launch_bounds__(NTHR, 1) scan_kernel(
    const float* __restrict__ inp, const float* __restrict__ hn,
    const float* __restrict__ inhib, const float* __restrict__ inp_weight,
    const unsigned short* __restrict__ Whi_g, const unsigned short* __restrict__ Wlo_g,
    unsigned short* __restrict__ ringH, unsigned short* __restrict__ ringL,
    float* __restrict__ rnn_out, unsigned* __restrict__ cnt)
{
  extern __shared__ char smem[];
  int wg = blockIdx.x;
  int type = wg >> 5, tile = wg & 31;
  switch (type) {
    case 0: scan_body<3>(inp,hn,inhib,inp_weight,Whi_g,Wlo_g,ringH,ringL,rnn_out,cnt,smem,0,tile,0,4,5,0);       break;
    case 1: scan_body<1>(inp,hn,inhib,inp_weight,Whi_g,Wlo_g,ringH,ringL,rnn_out,cnt,smem,1,tile,0,0,0,786432);  break;
    case 2: scan_body<1>(inp,hn,inhib,inp_weight,Whi_g,Wlo_g,ringH,ringL,rnn_out,cnt,smem,2,tile,1,0,0,1048576); break;
    case 3: scan_body<2>(inp,hn,inhib,inp_weight,Whi_g,Wlo_g,ringH,ringL,rnn_out,cnt,smem,3,tile,0,2,0,1310720); break;
    case 4: scan_body<1>(inp,hn,inhib,inp_weight,Whi_g,Wlo_g,ringH,ringL,rnn_out,cnt,smem,4,tile,3,0,0,1835008); break;
    default:scan_body<2>(inp,hn,inhib,inp_weight,Whi_g,Wlo_g,ringH,ringL,rnn_out,cnt,smem,5,tile,4,5,0,2097152); break;
  }
}

// ============================ head kernel ============================
__global__ void head_kernel(const float* __restrict__ rnn, const float* __restrict__ fc_vec,
                            float* __restrict__ out, float* __restrict__ hn_last)
{
  int lane = threadIdx.x & 63;
  if (blockIdx.x < 4000) {
    int wid = blockIdx.x * 4 + (threadIdx.x >> 6);
    int b = wid / 1000, t = wid - b * 1000;
    const float* rp = rnn + (size_t)(b * 1000 + t) * H6 + 2560 + lane * 8;
    float4 a0 = *(const float4*)rp, a1 = *(const float4*)(rp + 4);
    const float* vp = fc_vec + lane * 8;
    float4 v0 = *(const float4*)vp, v1 = *(const float4*)(vp + 4);
    float s = a0.x*v0.x + a0.y*v0.y + a0.z*v0.z + a0.w*v0.w
            + a1.x*v1.x + a1.y*v1.y + a1.z*v1.z + a1.w*v1.w;
    for (int off = 32; off; off >>= 1) s += __shfl_down(s, off);
    if (lane == 0) out[b * 1000 + t] = 1.f / (1.f + expf(-s));
  } else {
    int idx = (blockIdx.x - 4000) * NTHR + threadIdx.x;
    int b = idx / H6, j = idx - b * H6;
    hn_last[idx] = rnn[(size_t)(b * 1000 + 999) * H6 + j];
  }
}

// ============================ x broadcast ============================
__global__ void bcast_kernel(const float* __restrict__ x,
                             float* __restrict__ x_last, float* __restrict__ x_out)
{
  int gid = blockIdx.x * blockDim.x + threadIdx.x;
  int stride = gridDim.x * blockDim.x;
  for (int i = gid; i < 12288; i += stride)
    ((float4*)x_last)[i] = ((const float4*)x)[i];
  for (int i = gid; i < 12288000; i += stride) {
    int b = i / 768000;
    int r = i - b * 768000;
    int j4 = r % 768;
    ((float4*)x_out)[i] = ((const float4*)x)[b * 768 + j4];
  }
}

// ============================ launcher ============================
extern "C" void kernel_launch(void* const* d_in, const int* in_sizes, int n_in,
                              void* d_out, int out_size, void* d_ws, size_t ws_size,
                              hipStream_t stream) {
  (void)in_sizes; (void)n_in; (void)out_size; (void)ws_size;
  const float* inp        = (const float*)d_in[0];
  const float* hn         = (const float*)d_in[1];
  const float* x          = (const float*)d_in[2];
  const float* inhib      = (const float*)d_in[3];
  /* d_in[4] = str2str_w — unused (D = -I path uses str2str_fixed) */
  const float* thal2alm_w = (const float*)d_in[5];
  const float* thal2str_w = (const float*)d_in[6];
  const float* alm2alm_w  = (const float*)d_in[7];
  const float* alm2str_w  = (const float*)d_in[8];
  const float* str2snr_w  = (const float*)d_in[9];
  const float* str2gpe_w  = (const float*)d_in[10];
  const float* gpe2stn_w  = (const float*)d_in[11];
  const float* stn2snr_w  = (const float*)d_in[12];
  const float* snr2thal_w = (const float*)d_in[13];
  const float* inp_weight = (const float*)d_in[14];
  const float* fc1        = (const float*)d_in[15];
  const float* fc2        = (const float*)d_in[16];
  const float* fixed_     = (const float*)d_in[17];

  float* out_p   = (float*)d_out;
  float* hn_last = out_p + 16000;
  float* rnn     = hn_last + 49152;
  float* x_last  = rnn + 49152000;
  float* x_out   = x_last + 49152;

  char* ws = (char*)d_ws;
  unsigned short* Whi   = (unsigned short*)(ws);
  unsigned short* Wlo   = (unsigned short*)(ws + WS_WLO);
  unsigned short* ringH = (unsigned short*)(ws + WS_RHI);
  unsigned short* ringL = (unsigned short*)(ws + WS_RLO);
  float* fc_vec = (float*)(ws + WS_FCV);
  unsigned* cnt = (unsigned*)(ws + WS_CNT);

  hipFuncSetAttribute((const void*)scan_kernel,
                      hipFuncAttributeMaxDynamicSharedMemorySize, 135168);

  prep_kernel<<<2048, NTHR, 0, stream>>>(hn, fixed_, thal2alm_w, thal2str_w, alm2alm_w,
      alm2str_w, str2snr_w, str2gpe_w, gpe2stn_w, stn2snr_w, snr2thal_w, fc1, fc2,
      Whi, Wlo, ringH, ringL, fc_vec, cnt);
  scan_kernel<<<NWG, NTHR, 134144, stream>>>(inp, hn, inhib, inp_weight,
      Whi, Wlo, ringH, ringL, rnn, cnt);
  head_kernel<<<4192, NTHR, 0, stream>>>(rnn, fc_vec, out_p, hn_last);
  bcast_kernel<<<4096, NTHR, 0, stream>>>(x, x_last, x_out);
}

// Round 3
// 7258.923 us; speedup vs baseline: 3.6297x; 1.2379x over previous
//
#include <hip/hip_runtime.h>

#define H6   3072
#define TT   1000
#define NWG  192
#define NTHR 256

typedef short bf16x8 __attribute__((ext_vector_type(8)));
typedef float f32x4  __attribute__((ext_vector_type(4)));

// ---- bf16 helpers (manual bits; RNE) ----
__device__ __forceinline__ unsigned short f2bf(float f) {
  unsigned u = __float_as_uint(f);
  return (unsigned short)((u + 0x7fffu + ((u >> 16) & 1u)) >> 16);
}
__device__ __forceinline__ float bf2f(unsigned short s) {
  return __uint_as_float(((unsigned)s) << 16);
}

// ---- workspace layout (bytes) ----
// Whi   : 2621440 bf16 = 5242880       @ 0
// Wlo   : 5242880                       @ 5242880
// ringH : 8 slots * 49152 bf16 = 786432 @ 10485760
// ringL : 786432                        @ 11272192
// fc_v  : 512 f32 = 2048                @ 12058624
// flags : 6 reg * 8 slot * 32 wg * u32  @ 12060672  (each reg-slot = own 128B line)
#define WS_WLO 5242880
#define WS_RHI 10485760
#define WS_RLO 11272192
#define WS_FCV 12058624
#define WS_FLG 12060672

// ============================ prep kernel ============================
__global__ void prep_kernel(
    const float* __restrict__ hn, const float* __restrict__ fixed_,
    const float* __restrict__ thal2alm_w, const float* __restrict__ thal2str_w,
    const float* __restrict__ alm2alm_w, const float* __restrict__ alm2str_w,
    const float* __restrict__ str2snr_w, const float* __restrict__ str2gpe_w,
    const float* __restrict__ gpe2stn_w, const float* __restrict__ stn2snr_w,
    const float* __restrict__ snr2thal_w,
    const float* __restrict__ fc1, const float* __restrict__ fc2,
    unsigned short* __restrict__ Whi, unsigned short* __restrict__ Wlo,
    unsigned short* __restrict__ ringH, unsigned short* __restrict__ ringL,
    float* __restrict__ fc_vec, unsigned* __restrict__ flags)
{
  int gid = blockIdx.x * blockDim.x + threadIdx.x;
  int stride = gridDim.x * blockDim.x;
  const int nbt[6]  = {3,1,1,2,1,2};
  const int woff[6] = {0,786432,1048576,1310720,1835008,2097152};
  for (int idx = gid; idx < 2621440; idx += stride) {
    int u = idx >> 18;
    int t = (u<3)?0:((u<4)?1:((u<5)?2:((u<7)?3:((u<8)?4:5))));
    int local = idx - woff[t];
    int ktot = nbt[t] << 9;
    int j  = local / ktot;
    int kx = local - j*ktot;
    int bi = kx >> 9, kk = kx & 511;
    int src = j*512 + kk;
    float w;
    if (t == 0) {       // str rows: [str | thal | alm]
      if (bi == 0)      w = -fixed_[src];
      else if (bi == 1) w = (j >= 128 && j < 384) ? fmaxf(thal2str_w[src],0.f) : 0.f;
      else              w = (kk < 359) ? fmaxf(alm2str_w[src],0.f) : 0.f;
    } else if (t == 1)  w = (kk >= 256) ? -fmaxf(str2gpe_w[src],0.f) : 0.f;
    else if (t == 2)    w = -fmaxf(gpe2stn_w[src],0.f);
    else if (t == 3)    w = (bi == 0) ? ((kk < 256) ? -fmaxf(str2snr_w[src],0.f) : 0.f)
                                      : fmaxf(stn2snr_w[src],0.f);
    else if (t == 4)    w = -fmaxf(snr2thal_w[src],0.f);
    else                w = (bi == 0) ? fmaxf(thal2alm_w[src],0.f)
                                      : fmaxf(alm2alm_w[src],0.f) * ((kk < 359) ? 1.f : -1.f);
    unsigned short hi = f2bf(w);
    Whi[idx] = hi;
    Wlo[idx] = f2bf(w - bf2f(hi));
  }
  // h0 = hn goes into ring slot 7 (== step -1 mod 8)
  for (int idx = gid; idx < 49152; idx += stride) {
    float v = hn[idx];
    unsigned short hi = f2bf(v);
    ringH[7*49152 + idx] = hi;
    ringL[7*49152 + idx] = f2bf(v - bf2f(hi));
  }
  int wid = gid >> 6, lane = gid & 63;
  if (wid < 512) {
    float s = 0.f;
    for (int m = lane; m < 512; m += 64)
      s += fmaxf(fc1[(2560 + wid)*512 + m], 0.f) * fmaxf(fc2[m], 0.f);
    for (int off = 32; off; off >>= 1) s += __shfl_down(s, off);
    if (lane == 0) fc_vec[wid] = s;
  }
  if (gid < 1536) flags[gid] = 0u;
}

// ============================ scan kernel ============================
// Barrier-free dataflow. Publish = each producer WG stores step+1 into its
// OWN word of the (region,slot) 128B flag line (no RMW, no false sharing --
// R2's packed fetch_add counters serialized ~192 RMWs/step on 3 cache lines
// = the 9us/step). Consumers poll with one coalesced 32-lane line read.
// Ring depth 8 vs max producer-consumer drift 5 (return-path bound) => safe.
template<int NB>
__device__ __forceinline__ void scan_body(
    const float* __restrict__ inp, const float* __restrict__ hn,
    const float* __restrict__ inhib, const float* __restrict__ inp_weight,
    const unsigned short* __restrict__ Whi_g, const unsigned short* __restrict__ Wlo_g,
    unsigned short* __restrict__ ringH, unsigned short* __restrict__ ringL,
    float* __restrict__ rnn_out, unsigned* __restrict__ flags,
    char* smem, int type, int tile, int kb0, int kb1, int kb2, int woff)
{
  const int tid = threadIdx.x, lane = tid & 63, wave = tid >> 6;
  const int ktot = NB << 9;
  const int jb_local = tile << 4;
  const int jb_glob  = (type << 9) + jb_local;
  const int kb[3] = {kb0, kb1, kb2};

  unsigned short* Wsh_hi = (unsigned short*)(smem);
  unsigned short* Wsh_lo = (unsigned short*)(smem + 49152);
  unsigned short* hsh_hi = (unsigned short*)(smem + 98304);
  unsigned short* hsh_lo = (unsigned short*)(smem + 114688);
  float*          red    = (float*)(smem + 131072);

  // ---- load W tile into LDS once (16B-chunk xor swizzle) ----
  {
    const int cpr = ktot >> 3;
    const unsigned short* srch = Whi_g + woff + jb_local * ktot;
    const unsigned short* srcl = Wlo_g + woff + jb_local * ktot;
    for (int c = tid; c < 16 * cpr; c += NTHR) {
      int j = c / cpr, kc = c - j * cpr;
      uint4 vh = *(const uint4*)(srch + j * ktot + (kc << 3));
      uint4 vl = *(const uint4*)(srcl + j * ktot + (kc << 3));
      int kcs = kc ^ (j & 7);
      *(uint4*)((char*)Wsh_hi + j * (ktot << 1) + (kcs << 4)) = vh;
      *(uint4*)((char*)Wsh_lo + j * (ktot << 1) + (kcs << 4)) = vl;
    }
  }

  // ---- per-lane epilogue constants (wave0; C/D: col=b=lane&15, row=quad*4+r) ----
  const int b_ep = lane & 15, quad = lane >> 4;
  const bool has_inp = (type == 0) && (jb_local >= 128) && (jb_local < 384);
  int jg[4]; float hprev[4], dbase[4], iw[4][4];
  #pragma unroll
  for (int r = 0; r < 4; ++r) {
    jg[r] = jb_glob + (quad << 2) + r;
    hprev[r] = hn[b_ep * H6 + jg[r]];
    float tn = ((jg[r] >= 512 && jg[r] < 1536) || (jg[r] >= 2048 && jg[r] < 2560)) ? 1.f : 0.f;
    dbase[r] = inhib[b_ep * H6 + jg[r]] + tn;
    #pragma unroll
    for (int i = 0; i < 4; ++i)
      iw[r][i] = has_inp ? fmaxf(inp_weight[i * H6 + jg[r]], 0.f) : 0.f;
  }
  __syncthreads();

  for (int t = 0; t < TT; ++t) {
    // ---- wait for source regions to publish step t-1 ----
    // wave bi polls source kb[bi]: 32-lane coalesced read of one 128B line.
    if (t > 0 && wave < NB) {
      const unsigned* line = &flags[((kb[wave] << 3) + ((t - 1) & 7)) << 5];
      for (;;) {
        unsigned v = 0xFFFFFFFFu;
        if (lane < 32)
          v = __hip_atomic_load(&line[lane], __ATOMIC_RELAXED, __HIP_MEMORY_SCOPE_AGENT);
        if (__all(v >= (unsigned)t)) break;
        __builtin_amdgcn_s_sleep(1);
      }
    }
    __syncthreads();   // sync A: gates h loads; also orders red/hsh reuse

    const int s_rd = (t + 7) & 7;  // (t-1) mod 8 ; t=0 -> slot 7 (hn from prep)
    // ---- load h for all source blocks (sc1 LLC loads, pipelined) ----
    unsigned long long vh[NB][4][2], vl[NB][4][2];
    #pragma unroll
    for (int bi = 0; bi < NB; ++bi) {
      const unsigned short* gh = ringH + s_rd * 49152 + (kb[bi] << 9);
      const unsigned short* gl = ringL + s_rd * 49152 + (kb[bi] << 9);
      #pragma unroll
      for (int i = 0; i < 4; ++i) {
        int b = wave + (i << 2);
        const unsigned long long* ph = (const unsigned long long*)(gh + b * H6 + (lane << 3));
        const unsigned long long* pl = (const unsigned long long*)(gl + b * H6 + (lane << 3));
        vh[bi][i][0] = __hip_atomic_load(ph,     __ATOMIC_RELAXED, __HIP_MEMORY_SCOPE_AGENT);
        vh[bi][i][1] = __hip_atomic_load(ph + 1, __ATOMIC_RELAXED, __HIP_MEMORY_SCOPE_AGENT);
        vl[bi][i][0] = __hip_atomic_load(pl,     __ATOMIC_RELAXED, __HIP_MEMORY_SCOPE_AGENT);
        vl[bi][i][1] = __hip_atomic_load(pl + 1, __ATOMIC_RELAXED, __HIP_MEMORY_SCOPE_AGENT);
      }
    }

    f32x4 acc0 = {0,0,0,0}, acc1 = {0,0,0,0}, acc2 = {0,0,0,0};
    #pragma unroll
    for (int bi = 0; bi < NB; ++bi) {
      if (bi) __syncthreads();
      #pragma unroll
      for (int i = 0; i < 4; ++i) {
        int b = wave + (i << 2);
        int kcs = lane ^ (b & 7);
        uint4 wh, wl;
        ((unsigned long long*)&wh)[0] = vh[bi][i][0];
        ((unsigned long long*)&wh)[1] = vh[bi][i][1];
        ((unsigned long long*)&wl)[0] = vl[bi][i][0];
        ((unsigned long long*)&wl)[1] = vl[bi][i][1];
        *(uint4*)((char*)hsh_hi + (b << 10) + (kcs << 4)) = wh;
        *(uint4*)((char*)hsh_lo + (b << 10) + (kcs << 4)) = wl;
      }
      __syncthreads();
      const int row = lane & 15;
      const int wpitch = ktot << 1;
      #pragma unroll
      for (int c = 0; c < 4; ++c) {
        int kca = (bi << 6) + (wave << 4) + (c << 2) + quad;
        int hca = (wave << 4) + (c << 2) + quad;
        bf16x8 ahi = *(const bf16x8*)((char*)Wsh_hi + row * wpitch + ((kca ^ (row & 7)) << 4));
        bf16x8 alo = *(const bf16x8*)((char*)Wsh_lo + row * wpitch + ((kca ^ (row & 7)) << 4));
        bf16x8 bhi = *(const bf16x8*)((char*)hsh_hi + (row << 10) + ((hca ^ (row & 7)) << 4));
        bf16x8 blo = *(const bf16x8*)((char*)hsh_lo + (row << 10) + ((hca ^ (row & 7)) << 4));
        acc0 = __builtin_amdgcn_mfma_f32_16x16x32_bf16(ahi, bhi, acc0, 0, 0, 0);
        acc1 = __builtin_amdgcn_mfma_f32_16x16x32_bf16(ahi, blo, acc1, 0, 0, 0);
        acc2 = __builtin_amdgcn_mfma_f32_16x16x32_bf16(alo, bhi, acc2, 0, 0, 0);
      }
    }
    f32x4 acc = acc0 + acc1 + acc2;

    // ---- cross-wave reduce ----
    if (wave) *(f32x4*)(red + ((wave - 1) * 64 + lane) * 4) = acc;
    __syncthreads();   // sync R
    if (wave == 0) {
      f32x4 r0 = *(const f32x4*)(red + lane * 4);
      f32x4 r1 = *(const f32x4*)(red + (64 + lane) * 4);
      f32x4 r2 = *(const f32x4*)(red + (128 + lane) * 4);
      acc = acc + r0 + r1 + r2;
      float proj[4] = {0.f, 0.f, 0.f, 0.f};
      if (has_inp) {
        const float4 xi = *(const float4*)(inp + (b_ep * TT + t) * 4);
        #pragma unroll
        for (int r = 0; r < 4; ++r)
          proj[r] = xi.x*iw[r][0] + xi.y*iw[r][1] + xi.z*iw[r][2] + xi.w*iw[r][3];
      }
      float4 hv4;
      unsigned long long ph = 0ull, pl = 0ull;
      #pragma unroll
      for (int r = 0; r < 4; ++r) {
        float pre = hprev[r] + 0.01f * (acc[r] + dbase[r] + proj[r] - hprev[r]);
        float hv = fmaxf(pre, 0.f);
        hprev[r] = hv;
        ((float*)&hv4)[r] = hv;
        unsigned short hi = f2bf(hv);
        ph |= ((unsigned long long)hi) << (16 * r);
        pl |= ((unsigned long long)f2bf(hv - bf2f(hi))) << (16 * r);
      }
      *(float4*)(rnn_out + (size_t)(b_ep * TT + t) * H6 + jg[0]) = hv4;  // plain, stays in L2
      unsigned long long* oh = (unsigned long long*)(ringH + (t & 7) * 49152 + b_ep * H6 + jg[0]);
      unsigned long long* ol = (unsigned long long*)(ringL + (t & 7) * 49152 + b_ep * H6 + jg[0]);
      __hip_atomic_store(oh, ph, __ATOMIC_RELAXED, __HIP_MEMORY_SCOPE_AGENT);
      __hip_atomic_store(ol, pl, __ATOMIC_RELAXED, __HIP_MEMORY_SCOPE_AGENT);
      asm volatile("s_waitcnt vmcnt(0)" ::: "memory");  // drain h stores before publish
      if (lane == 0)
        __hip_atomic_store(&flags[(((type << 3) + (t & 7)) << 5) + tile], (unsigned)(t + 1),
                           __ATOMIC_RELAXED, __HIP_MEMORY_SCOPE_AGENT);
    }
  }
}

__global__ void __launch_bounds__(NTHR, 1) scan_kernel(
    const float* __restrict__ inp, const float* __restrict__ hn,
    const float* __restrict__ inhib, const float* __restrict__ inp_weight,
    const unsigned short* __restrict__ Whi_g, const unsigned short* __restrict__ Wlo_g,
    unsigned short* __restrict__ ringH, unsigned short* __restrict__ ringL,
    float* __restrict__ rnn_out, unsigned* __restrict__ flags)
{
  extern __shared__ char smem[];
  int wg = blockIdx.x;
  int type = wg >> 5, tile = wg & 31;
  switch (type) {
    case 0: scan_body<3>(inp,hn,inhib,inp_weight,Whi_g,Wlo_g,ringH,ringL,rnn_out,flags,smem,0,tile,0,4,5,0);       break;
    case 1: scan_body<1>(inp,hn,inhib,inp_weight,Whi_g,Wlo_g,ringH,ringL,rnn_out,flags,smem,1,tile,0,0,0,786432);  break;
    case 2: scan_body<1>(inp,hn,inhib,inp_weight,Whi_g,Wlo_g,ringH,ringL,rnn_out,flags,smem,2,tile,1,0,0,1048576); break;
    case 3: scan_body<2>(inp,hn,inhib,inp_weight,Whi_g,Wlo_g,ringH,ringL,rnn_out,flags,smem,3,tile,0,2,0,1310720); break;
    case 4: scan_body<1>(inp,hn,inhib,inp_weight,Whi_g,Wlo_g,ringH,ringL,rnn_out,flags,smem,4,tile,3,0,0,1835008); break;
    default:scan_body<2>(inp,hn,inhib,inp_weight,Whi_g,Wlo_g,ringH,ringL,rnn_out,flags,smem,5,tile,4,5,0,2097152); break;
  }
}

// ============================ head kernel ============================
__global__ void head_kernel(const float* __restrict__ rnn, const float* __restrict__ fc_vec,
                            float* __restrict__ out, float* __restrict__ hn_last)
{
  int lane = threadIdx.x & 63;
  if (blockIdx.x < 4000) {
    int wid = blockIdx.x * 4 + (threadIdx.x >> 6);
    int b = wid / 1000, t = wid - b * 1000;
    const float* rp = rnn + (size_t)(b * 1000 + t) * H6 + 2560 + lane * 8;
    float4 a0 = *(const float4*)rp, a1 = *(const float4*)(rp + 4);
    const float* vp = fc_vec + lane * 8;
    float4 v0 = *(const float4*)vp, v1 = *(const float4*)(vp + 4);
    float s = a0.x*v0.x + a0.y*v0.y + a0.z*v0.z + a0.w*v0.w
            + a1.x*v1.x + a1.y*v1.y + a1.z*v1.z + a1.w*v1.w;
    for (int off = 32; off; off >>= 1) s += __shfl_down(s, off);
    if (lane == 0) out[b * 1000 + t] = 1.f / (1.f + expf(-s));
  } else {
    int idx = (blockIdx.x - 4000) * NTHR + threadIdx.x;
    int b = idx / H6, j = idx - b * H6;
    hn_last[idx] = rnn[(size_t)(b * 1000 + 999) * H6 + j];
  }
}

// ============================ x broadcast ============================
__global__ void bcast_kernel(const float* __restrict__ x,
                             float* __restrict__ x_last, float* __restrict__ x_out)
{
  int gid = blockIdx.x * blockDim.x + threadIdx.x;
  int stride = gridDim.x * blockDim.x;
  for (int i = gid; i < 12288; i += stride)
    ((float4*)x_last)[i] = ((const float4*)x)[i];
  for (int i = gid; i < 12288000; i += stride) {
    int b = i / 768000;
    int r = i - b * 768000;
    int j4 = r % 768;
    ((float4*)x_out)[i] = ((const float4*)x)[b * 768 + j4];
  }
}

// ============================ launcher ============================
extern "C" void kernel_launch(void* const* d_in, const int* in_sizes, int n_in,
                              void* d_out, int out_size, void* d_ws, size_t ws_size,
                              hipStream_t stream) {
  (void)in_sizes; (void)n_in; (void)out_size; (void)ws_size;
  const float* inp        = (const float*)d_in[0];
  const float* hn         = (const float*)d_in[1];
  const float* x          = (const float*)d_in[2];
  const float* inhib      = (const float*)d_in[3];
  /* d_in[4] = str2str_w — unused (D = -I path uses str2str_fixed) */
  const float* thal2alm_w = (const float*)d_in[5];
  const float* thal2str_w = (const float*)d_in[6];
  const float* alm2alm_w  = (const float*)d_in[7];
  const float* alm2str_w  = (const float*)d_in[8];
  const float* str2snr_w  = (const float*)d_in[9];
  const float* str2gpe_w  = (const float*)d_in[10];
  const float* gpe2stn_w  = (const float*)d_in[11];
  const float* stn2snr_w  = (const float*)d_in[12];
  const float* snr2thal_w = (const float*)d_in[13];
  const float* inp_weight = (const float*)d_in[14];
  const float* fc1        = (const float*)d_in[15];
  const float* fc2        = (const float*)d_in[16];
  const float* fixed_     = (const float*)d_in[17];

  float* out_p   = (float*)d_out;
  float* hn_last = out_p + 16000;
  float* rnn     = hn_last + 49152;
  float* x_last  = rnn + 49152000;
  float* x_out   = x_last + 49152;

  char* ws = (char*)d_ws;
  unsigned short* Whi   = (unsigned short*)(ws);
  unsigned short* Wlo   = (unsigned short*)(ws + WS_WLO);
  unsigned short* ringH = (unsigned short*)(ws + WS_RHI);
  unsigned short* ringL = (unsigned short*)(ws + WS_RLO);
  float* fc_vec   = (float*)(ws + WS_FCV);
  unsigned* flags = (unsigned*)(ws + WS_FLG);

  hipFuncSetAttribute((const void*)scan_kernel,
                      hipFuncAttributeMaxDynamicSharedMemorySize, 135168);

  prep_kernel<<<2048, NTHR, 0, stream>>>(hn, fixed_, thal2alm_w, thal2str_w, alm2alm_w,
      alm2str_w, str2snr_w, str2gpe_w, gpe2stn_w, stn2snr_w, snr2thal_w, fc1, fc2,
      Whi, Wlo, ringH, ringL, fc_vec, flags);
  scan_kernel<<<NWG, NTHR, 134144, stream>>>(inp, hn, inhib, inp_weight,
      Whi, Wlo, ringH, ringL, rnn, flags);
  head_kernel<<<4192, NTHR, 0, stream>>>(rnn, fc_vec, out_p, hn_last);
  bcast_kernel<<<4096, NTHR, 0, stream>>>(x, x_last, x_out);
}